// Round 3
// baseline (1025.705 us; speedup 1.0000x reference)
//
#include <hip/hip_runtime.h>
#include <stdint.h>
#include <stddef.h>

#define A_N 384
#define F_N 128
#define C_N 32
#define H_N 512
#define LN_EPS 1e-5f

typedef unsigned short u16;
typedef _Float16 f16;
typedef f16 f16x8 __attribute__((ext_vector_type(8)));
typedef float f32x4 __attribute__((ext_vector_type(4)));
typedef int   i32x4 __attribute__((ext_vector_type(4)));   // native vec for nontemporal builtins

// ---- scratch in static device memory (d_ws unused) ----
__device__ float g_left[A_N * C_N];
__device__ float g_right[A_N * C_N];
__device__ float g_M[A_N * F_N * C_N];      // [b][f][c] fp32
__device__ f16   gW1T[H_N * F_N];           // [h][k]  = w_t1[k][h]   (fp16)
__device__ f16   gW2T[F_N * H_N];           // [f][h]  = w_t2[h][f]   (fp16)

__device__ __forceinline__ float b2f(u16 u) {
    union { float f; uint32_t i; } v; v.i = ((uint32_t)u) << 16; return v.f;
}
__device__ __forceinline__ float ld(const void* p, int idx, bool isbf) {
    if (isbf) return b2f(((const u16*)p)[idx]);
    return ((const float*)p)[idx];
}
__device__ __forceinline__ bool probe_bf16(const void* node_mask) {
    return ((const u16*)node_mask)[0] == 0x3F80u;   // 1.0 bf16; fp32 LE low half is 0x0000
}
// 8 consecutive elems of edge_vec, dtype-adaptive, NONTEMPORAL (stream-once, keep out of L2)
__device__ __forceinline__ void ldE8(const void* p, size_t idx, bool isbf, float4& lo, float4& hi) {
    if (isbf) {
        union { i32x4 v; u16 h[8]; } u;
        u.v = __builtin_nontemporal_load((const i32x4*)((const u16*)p + idx));
        lo = make_float4(b2f(u.h[0]), b2f(u.h[1]), b2f(u.h[2]), b2f(u.h[3]));
        hi = make_float4(b2f(u.h[4]), b2f(u.h[5]), b2f(u.h[6]), b2f(u.h[7]));
    } else {
        const i32x4* q = (const i32x4*)((const float*)p + idx);
        union { i32x4 v; float4 f; } a, b;
        a.v = __builtin_nontemporal_load(q);
        b.v = __builtin_nontemporal_load(q + 1);
        lo = a.f; hi = b.f;
    }
}
__device__ __forceinline__ f16x8 ldfrag(const void* p) {
    union { int4 i; f16x8 h; } u; u.i = *(const int4*)p; return u.h;
}

// ---------------- K1: node LN + left/right projections (proven) ----------------
__global__ void k_leftright(const void* __restrict__ node_vec, const void* __restrict__ node_mask,
                            const void* __restrict__ op_scale, const void* __restrict__ op_bias,
                            const void* __restrict__ w_left, const void* __restrict__ b_left,
                            const void* __restrict__ w_right, const void* __restrict__ b_right) {
    bool isbf = probe_bf16(node_mask);
    int a = blockIdx.x;
    int f = threadIdx.x;            // 128 threads = 2 waves
    __shared__ float sAct[F_N];
    __shared__ float sRed[4];
    float x = ld(node_vec, a * F_N + f, isbf);
    float s1 = x, s2 = x * x;
    for (int o = 1; o < 64; o <<= 1) { s1 += __shfl_xor(s1, o); s2 += __shfl_xor(s2, o); }
    int wv = threadIdx.x >> 6;
    if ((threadIdx.x & 63) == 0) { sRed[wv * 2] = s1; sRed[wv * 2 + 1] = s2; }
    __syncthreads();
    float sum = sRed[0] + sRed[2], sq = sRed[1] + sRed[3];
    float mu = sum * (1.0f / F_N);
    float var = sq * (1.0f / F_N) - mu * mu;
    float rs = rsqrtf(var + LN_EPS);
    sAct[f] = (x - mu) * rs * ld(op_scale, f, isbf) + ld(op_bias, f, isbf);
    __syncthreads();
    if (threadIdx.x < 64) {
        int c = threadIdx.x & 31;
        bool isL = threadIdx.x < 32;
        const void* W = isL ? w_left : w_right;
        const void* B = isL ? b_left : b_right;
        float acc = ld(B, c, isbf);
        for (int ff = 0; ff < F_N; ff++) acc += sAct[ff] * ld(W, ff * C_N + c, isbf);
        acc *= ld(node_mask, a, isbf);
        float* dst = isL ? g_left : g_right;
        dst[a * C_N + c] = acc;
    }
}

// ---------------- K2: M[b][f][c] = sum_d right[b,d] * w_out[(c*32+d), f] ----------------
// ILP version: 32 independent accumulators, 32 independent loads per d step.
__global__ void k_M(const void* __restrict__ w_out, const void* __restrict__ node_mask) {
    bool isbf = probe_bf16(node_mask);
    int b = blockIdx.x;
    int f = threadIdx.x;            // 128 threads
    __shared__ float sR[C_N];
    if (f < C_N) sR[f] = g_right[b * C_N + f];
    __syncthreads();
    float acc[C_N];
    #pragma unroll
    for (int c = 0; c < C_N; c++) acc[c] = 0.f;
    for (int d = 0; d < C_N; d++) {
        float rv = sR[d];
        #pragma unroll
        for (int c = 0; c < C_N; c++)
            acc[c] += rv * ld(w_out, (c * C_N + d) * F_N + f, isbf);
    }
    #pragma unroll
    for (int c = 0; c < C_N; c++) g_M[((size_t)b * F_N + f) * C_N + c] = acc[c];
}

// ---------------- K2b: pre-transpose MLP weights to fp16 ----------------
__global__ void k_wt(const void* __restrict__ w_t1, const void* __restrict__ w_t2,
                     const void* __restrict__ node_mask) {
    bool isbf = probe_bf16(node_mask);
    int t = blockIdx.x * 256 + threadIdx.x;     // 0..65535
    int h = t >> 7, k = t & 127;
    gW1T[t] = (f16)ld(w_t1, k * H_N + h, isbf);
    int f2 = t >> 9, h2 = t & 511;
    gW2T[t] = (f16)ld(w_t2, h2 * F_N + f2, isbf);
}

// ---------------- K3: fused edge + LN + MLP + residual ----------------
// 512 threads (8 waves), tile = 128 rows = 16 a x 8 b. Wave grid 4x2 (wr 0..3 rows, wc 0..1 f-half).
// E computed on VALU, raw E streamed to out[] (residual read back in epilogue, L2-resident).
// LayerNorm fully in-register (shfl over the 16-lane f-group) -> no fp32 sE buffer.
// LDS map (51.5 KB total, 2+ blocks/CU):
//   @0     : sX f16[128][128] rows 256B (phases 1-2)          | phase 3+: W1 f16[64n][128k] 16KB
//   @16384 :                                                   W2 f16[128f][64h] 16KB
//   @32768 : sLeft fp32[16][32] 2KB, sBout 512B (phase 1 only)| phase 3+: H f16[128r][64h] 16KB
//   @49152 : persistent consts: sB1[512] 2KB | sScale | sBias | sB2  (3.5KB)
// All tiles: byte ^= (row&7)<<4 XOR swizzle on write AND read.
#define SM_W2   16384
#define SM_H    32768
#define SM_LEFT 32768
#define SM_BOUT 34816
#define SM_B1   49152
#define SM_SCL  51200
#define SM_BIA  51712
#define SM_B2   52224
#define SM_TOT  52736

__global__ __launch_bounds__(512, 4) void k_fused(
    const void* __restrict__ edge_vec, const void* __restrict__ b_out,
    const void* __restrict__ tr_scale, const void* __restrict__ tr_bias,
    const void* __restrict__ b_t1, const void* __restrict__ b_t2,
    const void* __restrict__ node_mask, float* __restrict__ out)
{
    bool isbf = probe_bf16(node_mask);
    __shared__ __align__(16) unsigned char smem[SM_TOT];
    float* sB1    = (float*)(smem + SM_B1);
    float* sScale = (float*)(smem + SM_SCL);
    float* sBias  = (float*)(smem + SM_BIA);
    float* sB2    = (float*)(smem + SM_B2);
    float* sLeft  = (float*)(smem + SM_LEFT);
    float* sBout  = (float*)(smem + SM_BOUT);

    const int t = threadIdx.x;              // 512 threads = 8 waves
    const int lane = t & 63, wid = t >> 6;
    const int a0 = blockIdx.y * 16, b0 = blockIdx.x * 8;

    // ---- phase 0: stage consts + left tile ----
    sB1[t] = ld(b_t1, t, isbf);
    if (t < 128) {
        sScale[t] = ld(tr_scale, t, isbf);
        sBias[t]  = ld(tr_bias, t, isbf);
        sBout[t]  = ld(b_out, t, isbf);
        sB2[t]    = ld(b_t2, t, isbf);
    }
    {
        int ai = t >> 5, c = t & 31;        // 512 threads = 16 a x 32 c exactly
        sLeft[ai * 32 + c] = g_left[(a0 + ai) * C_N + c];
    }
    __syncthreads();

    // ---- phase 1: E = edge + left.M + bout -> out[] (raw, fp32) ; LN in-register -> sX f16 ----
    {
        const int fg = t & 15, bi = (t >> 4) & 7, ag = t >> 7;   // ag 0..3
        const int f0 = fg * 8;
        const int b = b0 + bi;
        float acc[4][8];
        #pragma unroll
        for (int ii = 0; ii < 4; ii++) {
            int a = a0 + ag * 4 + ii;
            size_t rG = ((size_t)a * A_N + b) * F_N + f0;
            float4 lo, hi;
            ldE8(edge_vec, rG, isbf, lo, hi);
            acc[ii][0] = lo.x + sBout[f0+0]; acc[ii][1] = lo.y + sBout[f0+1];
            acc[ii][2] = lo.z + sBout[f0+2]; acc[ii][3] = lo.w + sBout[f0+3];
            acc[ii][4] = hi.x + sBout[f0+4]; acc[ii][5] = hi.y + sBout[f0+5];
            acc[ii][6] = hi.z + sBout[f0+6]; acc[ii][7] = hi.w + sBout[f0+7];
        }
        const float4* Mv = (const float4*)(g_M + ((size_t)b * F_N + f0) * C_N); // Mv[j*8+cv]
        #pragma unroll
        for (int cv = 0; cv < 8; cv++) {
            float4 L0 = *(const float4*)&sLeft[(ag * 4 + 0) * 32 + cv * 4];
            float4 L1 = *(const float4*)&sLeft[(ag * 4 + 1) * 32 + cv * 4];
            float4 L2 = *(const float4*)&sLeft[(ag * 4 + 2) * 32 + cv * 4];
            float4 L3 = *(const float4*)&sLeft[(ag * 4 + 3) * 32 + cv * 4];
            #pragma unroll
            for (int j = 0; j < 8; j++) {
                float4 m4 = Mv[j * 8 + cv];
                acc[0][j] += L0.x*m4.x + L0.y*m4.y + L0.z*m4.z + L0.w*m4.w;
                acc[1][j] += L1.x*m4.x + L1.y*m4.y + L1.z*m4.z + L1.w*m4.w;
                acc[2][j] += L2.x*m4.x + L2.y*m4.y + L2.z*m4.z + L2.w*m4.w;
                acc[3][j] += L3.x*m4.x + L3.y*m4.y + L3.z*m4.z + L3.w*m4.w;
            }
        }
        #pragma unroll
        for (int ii = 0; ii < 4; ii++) {
            int a = a0 + ag * 4 + ii;
            int r = (ag * 4 + ii) * 8 + bi;
            // raw E -> out (coalesced: 16 fg-lanes x 32B = 512B contiguous)
            size_t rG = ((size_t)a * A_N + b) * F_N + f0;
            *(float4*)(out + rG)     = make_float4(acc[ii][0], acc[ii][1], acc[ii][2], acc[ii][3]);
            *(float4*)(out + rG + 4) = make_float4(acc[ii][4], acc[ii][5], acc[ii][6], acc[ii][7]);
            // in-register LayerNorm over f (reduce across the 16 fg lanes)
            float s1 = 0.f, s2 = 0.f;
            #pragma unroll
            for (int j = 0; j < 8; j++) { s1 += acc[ii][j]; s2 += acc[ii][j] * acc[ii][j]; }
            s1 += __shfl_xor(s1, 1); s2 += __shfl_xor(s2, 1);
            s1 += __shfl_xor(s1, 2); s2 += __shfl_xor(s2, 2);
            s1 += __shfl_xor(s1, 4); s2 += __shfl_xor(s2, 4);
            s1 += __shfl_xor(s1, 8); s2 += __shfl_xor(s2, 8);
            float mu = s1 * (1.0f / F_N);
            float var = s2 * (1.0f / F_N) - mu * mu;
            float rs = rsqrtf(var + LN_EPS);
            union { int4 i; f16x8 h; } hx;
            #pragma unroll
            for (int j = 0; j < 8; j++)
                hx.h[j] = (f16)((acc[ii][j] - mu) * rs * sScale[f0 + j] + sBias[f0 + j]);
            int byte = (fg * 16) ^ ((r & 7) << 4);
            *(int4*)(smem + r * 256 + byte) = hx.i;
        }
    }
    __syncthreads();

    // ---- phase 2: load X A-fragments to regs; acc2 = 0 ----
    const int wr = wid >> 1, wc = wid & 1;   // wave grid 4x2
    f16x8 a1[2][4];
    #pragma unroll
    for (int mr = 0; mr < 2; mr++)
        #pragma unroll
        for (int ks = 0; ks < 4; ks++) {
            int r = wr * 32 + mr * 16 + (lane & 15);
            int byte = (ks * 64 + (lane >> 4) * 16) ^ ((r & 7) << 4);
            a1[mr][ks] = ldfrag(smem + r * 256 + byte);
        }
    f32x4 acc2[2][4];
    #pragma unroll
    for (int mr = 0; mr < 2; mr++)
        #pragma unroll
        for (int nc = 0; nc < 4; nc++)
            acc2[mr][nc] = (f32x4){0.f, 0.f, 0.f, 0.f};
    __syncthreads();   // sX region now dead -> W1; sLeft region dead -> H

    // ---- phase 3: hidden chunks of 64 ----
    for (int ch = 0; ch < 8; ch++) {
        int h0 = ch * 64;
        // stage W1 chunk [64 n][128 k] (rows 256B) and W2 chunk [128 f][64 h] (rows 128B)
        {
            int n = t >> 3, sg = t & 7;                       // 8 x 32B per 256B row
            const int4* src = (const int4*)(gW1T + (size_t)(h0 + n) * F_N) + sg * 2;
            int byte = (sg * 32) ^ ((n & 7) << 4);
            *(int4*)(smem + n * 256 + byte)      = src[0];
            *(int4*)(smem + n * 256 + (byte^16)) = src[1];
            int f = t >> 2, sg2 = t & 3;                      // 4 x 32B per 128B row
            const int4* s2 = (const int4*)(gW2T + (size_t)f * H_N + h0) + sg2 * 2;
            int byte2 = (sg2 * 32) ^ ((f & 7) << 4);
            *(int4*)(smem + SM_W2 + f * 128 + byte2)      = s2[0];
            *(int4*)(smem + SM_W2 + f * 128 + (byte2^16)) = s2[1];
        }
        __syncthreads();

        // GEMM1: H_chunk[128r x 64h] = X @ W1chunk ; wave tile 32x32
        f32x4 acc1[2][2];
        #pragma unroll
        for (int mr = 0; mr < 2; mr++)
            #pragma unroll
            for (int nc = 0; nc < 2; nc++)
                acc1[mr][nc] = (f32x4){0.f, 0.f, 0.f, 0.f};
        __builtin_amdgcn_s_setprio(1);
        #pragma unroll
        for (int ks = 0; ks < 4; ks++) {
            f16x8 bfr[2];
            #pragma unroll
            for (int nc = 0; nc < 2; nc++) {
                int n = wc * 32 + nc * 16 + (lane & 15);
                int byte = (ks * 64 + (lane >> 4) * 16) ^ ((n & 7) << 4);
                bfr[nc] = ldfrag(smem + n * 256 + byte);
            }
            #pragma unroll
            for (int mr = 0; mr < 2; mr++)
                #pragma unroll
                for (int nc = 0; nc < 2; nc++)
                    acc1[mr][nc] = __builtin_amdgcn_mfma_f32_16x16x32_f16(
                        a1[mr][ks], bfr[nc], acc1[mr][nc], 0, 0, 0);
        }
        __builtin_amdgcn_s_setprio(0);
        // bias + relu + store H (f16, rows 128B)
        #pragma unroll
        for (int mr = 0; mr < 2; mr++)
            #pragma unroll
            for (int nc = 0; nc < 2; nc++) {
                int jl = wc * 32 + nc * 16 + (lane & 15);
                float b1v = sB1[h0 + jl];
                #pragma unroll
                for (int reg = 0; reg < 4; reg++) {
                    int r = wr * 32 + mr * 16 + (lane >> 4) * 4 + reg;
                    float h = fmaxf(acc1[mr][nc][reg] + b1v, 0.f);
                    int byte = (jl * 2) ^ ((r & 7) << 4);
                    *(f16*)(smem + SM_H + r * 128 + byte) = (f16)h;
                }
            }
        __syncthreads();

        // GEMM2: acc2 += H_chunk @ W2chunk ; wave tile 32r x 64f
        __builtin_amdgcn_s_setprio(1);
        #pragma unroll
        for (int ks = 0; ks < 2; ks++) {
            f16x8 afr[2], bfr2[4];
            #pragma unroll
            for (int mr = 0; mr < 2; mr++) {
                int r = wr * 32 + mr * 16 + (lane & 15);
                int byte = (ks * 64 + (lane >> 4) * 16) ^ ((r & 7) << 4);
                afr[mr] = ldfrag(smem + SM_H + r * 128 + byte);
            }
            #pragma unroll
            for (int nc = 0; nc < 4; nc++) {
                int f = wc * 64 + nc * 16 + (lane & 15);
                int byte = (ks * 64 + (lane >> 4) * 16) ^ ((f & 7) << 4);
                bfr2[nc] = ldfrag(smem + SM_W2 + f * 128 + byte);
            }
            #pragma unroll
            for (int mr = 0; mr < 2; mr++)
                #pragma unroll
                for (int nc = 0; nc < 4; nc++)
                    acc2[mr][nc] = __builtin_amdgcn_mfma_f32_16x16x32_f16(
                        afr[mr], bfr2[nc], acc2[mr][nc], 0, 0, 0);
        }
        __builtin_amdgcn_s_setprio(0);
        __syncthreads();
    }

    // ---- epilogue: out[a,b,f] = E (already there) + acc2 + b2 ----
    #pragma unroll
    for (int mr = 0; mr < 2; mr++)
        #pragma unroll
        for (int nc = 0; nc < 4; nc++)
            #pragma unroll
            for (int reg = 0; reg < 4; reg++) {
                int r = wr * 32 + mr * 16 + (lane >> 4) * 4 + reg;
                int f = wc * 64 + nc * 16 + (lane & 15);
                int a = a0 + (r >> 3), b = b0 + (r & 7);
                size_t idx = ((size_t)a * A_N + b) * F_N + f;
                out[idx] = out[idx] + acc2[mr][nc][reg] + sB2[f];
            }
}

extern "C" void kernel_launch(void* const* d_in, const int* in_sizes, int n_in,
                              void* d_out, int out_size, void* d_ws, size_t ws_size,
                              hipStream_t stream) {
    const void* node_vec  = d_in[0];
    const void* edge_vec  = d_in[1];
    const void* node_mask = d_in[2];
    // d_in[3] edge_mask: unused by reference
    const void* op_scale  = d_in[4];
    const void* op_bias   = d_in[5];
    const void* w_left    = d_in[6];
    const void* b_left    = d_in[7];
    const void* w_right   = d_in[8];
    const void* b_right   = d_in[9];
    const void* w_out     = d_in[10];
    const void* b_out     = d_in[11];
    const void* tr_scale  = d_in[12];
    const void* tr_bias   = d_in[13];
    const void* w_t1      = d_in[14];
    const void* b_t1      = d_in[15];
    const void* w_t2      = d_in[16];
    const void* b_t2      = d_in[17];
    float* out = (float*)d_out;
    (void)d_ws; (void)ws_size; (void)in_sizes; (void)n_in; (void)out_size;

    hipLaunchKernelGGL(k_leftright, dim3(A_N), dim3(128), 0, stream,
                       node_vec, node_mask, op_scale, op_bias,
                       w_left, b_left, w_right, b_right);
    hipLaunchKernelGGL(k_M, dim3(A_N), dim3(128), 0, stream, w_out, node_mask);
    hipLaunchKernelGGL(k_wt, dim3(256), dim3(256), 0, stream, w_t1, w_t2, node_mask);
    hipLaunchKernelGGL(k_fused, dim3(A_N / 8, A_N / 16), dim3(512), 0, stream,
                       edge_vec, b_out, tr_scale, tr_bias, b_t1, b_t2, node_mask, out);
}

// Round 4
// 612.057 us; speedup vs baseline: 1.6758x; 1.6758x over previous
//
#include <hip/hip_runtime.h>
#include <stdint.h>
#include <stddef.h>

#define A_N 384
#define F_N 128
#define C_N 32
#define H_N 512
#define LN_EPS 1e-5f

typedef unsigned short u16;
typedef _Float16 f16;
typedef f16 f16x8 __attribute__((ext_vector_type(8)));
typedef float f32x4 __attribute__((ext_vector_type(4)));
typedef int   i32x4 __attribute__((ext_vector_type(4)));   // native vec for nontemporal builtins

// ---- scratch in static device memory (d_ws unused) ----
__device__ float g_left[A_N * C_N];
__device__ float g_right[A_N * C_N];
__device__ float g_M[A_N * F_N * C_N];      // [b][f][c] fp32
__device__ f16   gW1T[H_N * F_N];           // [h][k]  = w_t1[k][h]       (fp16)
__device__ f16   gW2C[(H_N / 32) * F_N * 32]; // [ch][f][hh] = w_t2[ch*32+hh][f] (fp16, chunk-contiguous)

__device__ __forceinline__ float b2f(u16 u) {
    union { float f; uint32_t i; } v; v.i = ((uint32_t)u) << 16; return v.f;
}
__device__ __forceinline__ float ld(const void* p, int idx, bool isbf) {
    if (isbf) return b2f(((const u16*)p)[idx]);
    return ((const float*)p)[idx];
}
__device__ __forceinline__ bool probe_bf16(const void* node_mask) {
    return ((const u16*)node_mask)[0] == 0x3F80u;   // 1.0 bf16; fp32 LE low half is 0x0000
}
// 8 consecutive elems of edge_vec, dtype-adaptive, NONTEMPORAL (stream-once)
__device__ __forceinline__ void ldE8(const void* p, size_t idx, bool isbf, float4& lo, float4& hi) {
    if (isbf) {
        union { i32x4 v; u16 h[8]; } u;
        u.v = __builtin_nontemporal_load((const i32x4*)((const u16*)p + idx));
        lo = make_float4(b2f(u.h[0]), b2f(u.h[1]), b2f(u.h[2]), b2f(u.h[3]));
        hi = make_float4(b2f(u.h[4]), b2f(u.h[5]), b2f(u.h[6]), b2f(u.h[7]));
    } else {
        const i32x4* q = (const i32x4*)((const float*)p + idx);
        union { i32x4 v; float4 f; } a, b;
        a.v = __builtin_nontemporal_load(q);
        b.v = __builtin_nontemporal_load(q + 1);
        lo = a.f; hi = b.f;
    }
}
__device__ __forceinline__ void ntst4(float* p, float x, float y, float z, float w) {
    union { i32x4 v; float f[4]; } u;
    u.f[0] = x; u.f[1] = y; u.f[2] = z; u.f[3] = w;
    __builtin_nontemporal_store(u.v, (i32x4*)p);
}
__device__ __forceinline__ f16x8 ldfrag(const void* p) {
    union { int4 i; f16x8 h; } u; u.i = *(const int4*)p; return u.h;
}

// ---------------- K1: node LN + left/right projections (proven) ----------------
__global__ void k_leftright(const void* __restrict__ node_vec, const void* __restrict__ node_mask,
                            const void* __restrict__ op_scale, const void* __restrict__ op_bias,
                            const void* __restrict__ w_left, const void* __restrict__ b_left,
                            const void* __restrict__ w_right, const void* __restrict__ b_right) {
    bool isbf = probe_bf16(node_mask);
    int a = blockIdx.x;
    int f = threadIdx.x;            // 128 threads = 2 waves
    __shared__ float sAct[F_N];
    __shared__ float sRed[4];
    float x = ld(node_vec, a * F_N + f, isbf);
    float s1 = x, s2 = x * x;
    for (int o = 1; o < 64; o <<= 1) { s1 += __shfl_xor(s1, o); s2 += __shfl_xor(s2, o); }
    int wv = threadIdx.x >> 6;
    if ((threadIdx.x & 63) == 0) { sRed[wv * 2] = s1; sRed[wv * 2 + 1] = s2; }
    __syncthreads();
    float sum = sRed[0] + sRed[2], sq = sRed[1] + sRed[3];
    float mu = sum * (1.0f / F_N);
    float var = sq * (1.0f / F_N) - mu * mu;
    float rs = rsqrtf(var + LN_EPS);
    sAct[f] = (x - mu) * rs * ld(op_scale, f, isbf) + ld(op_bias, f, isbf);
    __syncthreads();
    if (threadIdx.x < 64) {
        int c = threadIdx.x & 31;
        bool isL = threadIdx.x < 32;
        const void* W = isL ? w_left : w_right;
        const void* B = isL ? b_left : b_right;
        float acc = ld(B, c, isbf);
        for (int ff = 0; ff < F_N; ff++) acc += sAct[ff] * ld(W, ff * C_N + c, isbf);
        acc *= ld(node_mask, a, isbf);
        float* dst = isL ? g_left : g_right;
        dst[a * C_N + c] = acc;
    }
}

// ---------------- K2: M[b][f][c] = sum_d right[b,d] * w_out[(c*32+d), f] ----------------
__global__ void k_M(const void* __restrict__ w_out, const void* __restrict__ node_mask) {
    bool isbf = probe_bf16(node_mask);
    int b = blockIdx.x;
    int f = threadIdx.x;            // 128 threads
    __shared__ float sR[C_N];
    if (f < C_N) sR[f] = g_right[b * C_N + f];
    __syncthreads();
    float acc[C_N];
    #pragma unroll
    for (int c = 0; c < C_N; c++) acc[c] = 0.f;
    for (int d = 0; d < C_N; d++) {
        float rv = sR[d];
        #pragma unroll
        for (int c = 0; c < C_N; c++)
            acc[c] += rv * ld(w_out, (c * C_N + d) * F_N + f, isbf);
    }
    #pragma unroll
    for (int c = 0; c < C_N; c++) g_M[((size_t)b * F_N + f) * C_N + c] = acc[c];
}

// ---------------- K2b: pre-transpose MLP weights to fp16 ----------------
// gW1T[h][k]       = w_t1[k][h]
// gW2C[ch][f][hh]  = w_t2[(ch*32+hh)][f]   (chunk-contiguous 8KB slabs)
__global__ void k_wt(const void* __restrict__ w_t1, const void* __restrict__ w_t2,
                     const void* __restrict__ node_mask) {
    bool isbf = probe_bf16(node_mask);
    int t = blockIdx.x * 256 + threadIdx.x;     // 0..65535
    int h = t >> 7, k = t & 127;
    gW1T[t] = (f16)ld(w_t1, k * H_N + h, isbf);
    int ch = t >> 12, rem = t & 4095, f2 = rem >> 5, hh = rem & 31;
    gW2C[t] = (f16)ld(w_t2, (ch * 32 + hh) * F_N + f2, isbf);
}

// ---------------- K3: fused edge + LN + MLP + residual ----------------
// 512 threads (8 waves), tile = 128 rows = 16 a x 8 b; row r: a-local = r>>3, b-local = r&7.
// Phase 1: E on VALU (coalesced NT edge loads), raw E NT-streamed to out[], LN in-register,
//          X f16 -> sX LDS (persistent through the chunk loop).
// Main loop: 16 chunks of 32 hidden units. Per chunk: stage W1ch(8K)+W2ch(8K) -> GEMM1
//          (waves 4r x 2h-half, 32x16 tiles) -> H(8K) -> GEMM2 (waves 4r x 2f-half, 32x64).
// Epilogue: out[idx] (NT) += acc2 + b2.
// LDS 62 KB: sX@0 (32K) | W1@32768 (8K) | W2@40960 (8K) | H@49152 (8K) | consts@57344.
#define SM_X    0
#define SM_W1   32768
#define SM_W2   40960
#define SM_H    49152
#define SM_B1   57344
#define SM_SCL  59392
#define SM_BIA  59904
#define SM_B2   60416
#define SM_BOUT 60928
#define SM_LEFT 61440
#define SM_TOT  63488

__global__ __launch_bounds__(512, 2) void k_fused(
    const void* __restrict__ edge_vec, const void* __restrict__ b_out,
    const void* __restrict__ tr_scale, const void* __restrict__ tr_bias,
    const void* __restrict__ b_t1, const void* __restrict__ b_t2,
    const void* __restrict__ node_mask, float* __restrict__ out)
{
    bool isbf = probe_bf16(node_mask);
    __shared__ __align__(16) unsigned char smem[SM_TOT];
    float* sB1    = (float*)(smem + SM_B1);
    float* sScale = (float*)(smem + SM_SCL);
    float* sBias  = (float*)(smem + SM_BIA);
    float* sB2    = (float*)(smem + SM_B2);
    float* sBout  = (float*)(smem + SM_BOUT);
    float* sLeft  = (float*)(smem + SM_LEFT);

    const int t = threadIdx.x;              // 512 threads = 8 waves
    const int lane = t & 63, wid = t >> 6;

    // Bijective XCD-aware remap: 1152 blocks = 8 xcd x (6 bx x 24 by).
    // Each XCD owns 6 consecutive b-tiles -> its g_M slice (48 b x 16KB = 768KB) is L2-resident.
    const int L = blockIdx.x;
    const int xcd = L & 7, pos = L >> 3;
    const int bx = xcd * 6 + (pos % 6);
    const int by = pos / 6;
    const int a0 = by * 16, b0 = bx * 8;

    // ---- phase 0: stage consts + left tile ----
    sB1[t] = ld(b_t1, t, isbf);
    if (t < 128) {
        sScale[t] = ld(tr_scale, t, isbf);
        sBias[t]  = ld(tr_bias, t, isbf);
        sBout[t]  = ld(b_out, t, isbf);
        sB2[t]    = ld(b_t2, t, isbf);
    }
    {
        int ai = t >> 5, c = t & 31;        // 512 = 16 a x 32 c exactly
        sLeft[ai * 32 + c] = g_left[(a0 + ai) * C_N + c];
    }
    __syncthreads();

    // ---- phase 1: E = edge + left.M + bout -> NT out[]; in-register LN -> sX f16 ----
    {
        const int fg = t & 15, bi = (t >> 4) & 7, ag = t >> 7;   // ag 0..3
        const int f0 = fg * 8;
        const int b = b0 + bi;
        float acc[4][8];
        #pragma unroll
        for (int ii = 0; ii < 4; ii++) {
            int a = a0 + ag * 4 + ii;
            size_t rG = ((size_t)a * A_N + b) * F_N + f0;
            float4 lo, hi;
            ldE8(edge_vec, rG, isbf, lo, hi);
            acc[ii][0] = lo.x + sBout[f0+0]; acc[ii][1] = lo.y + sBout[f0+1];
            acc[ii][2] = lo.z + sBout[f0+2]; acc[ii][3] = lo.w + sBout[f0+3];
            acc[ii][4] = hi.x + sBout[f0+4]; acc[ii][5] = hi.y + sBout[f0+5];
            acc[ii][6] = hi.z + sBout[f0+6]; acc[ii][7] = hi.w + sBout[f0+7];
        }
        const float4* Mv = (const float4*)(g_M + ((size_t)b * F_N + f0) * C_N); // Mv[j*8+cv]
        #pragma unroll
        for (int cv = 0; cv < 8; cv++) {
            float4 L0 = *(const float4*)&sLeft[(ag * 4 + 0) * 32 + cv * 4];
            float4 L1 = *(const float4*)&sLeft[(ag * 4 + 1) * 32 + cv * 4];
            float4 L2 = *(const float4*)&sLeft[(ag * 4 + 2) * 32 + cv * 4];
            float4 L3 = *(const float4*)&sLeft[(ag * 4 + 3) * 32 + cv * 4];
            #pragma unroll
            for (int j = 0; j < 8; j++) {
                float4 m4 = Mv[j * 8 + cv];
                acc[0][j] += L0.x*m4.x + L0.y*m4.y + L0.z*m4.z + L0.w*m4.w;
                acc[1][j] += L1.x*m4.x + L1.y*m4.y + L1.z*m4.z + L1.w*m4.w;
                acc[2][j] += L2.x*m4.x + L2.y*m4.y + L2.z*m4.z + L2.w*m4.w;
                acc[3][j] += L3.x*m4.x + L3.y*m4.y + L3.z*m4.z + L3.w*m4.w;
            }
        }
        #pragma unroll
        for (int ii = 0; ii < 4; ii++) {
            int a = a0 + ag * 4 + ii;
            int r = (ag * 4 + ii) * 8 + bi;
            size_t rG = ((size_t)a * A_N + b) * F_N + f0;
            // raw E -> out, nontemporal (re-read in epilogue; keep out of L2)
            ntst4(out + rG,     acc[ii][0], acc[ii][1], acc[ii][2], acc[ii][3]);
            ntst4(out + rG + 4, acc[ii][4], acc[ii][5], acc[ii][6], acc[ii][7]);
            // in-register LayerNorm over f (reduce across the 16 fg lanes)
            float s1 = 0.f, s2 = 0.f;
            #pragma unroll
            for (int j = 0; j < 8; j++) { s1 += acc[ii][j]; s2 += acc[ii][j] * acc[ii][j]; }
            s1 += __shfl_xor(s1, 1); s2 += __shfl_xor(s2, 1);
            s1 += __shfl_xor(s1, 2); s2 += __shfl_xor(s2, 2);
            s1 += __shfl_xor(s1, 4); s2 += __shfl_xor(s2, 4);
            s1 += __shfl_xor(s1, 8); s2 += __shfl_xor(s2, 8);
            float mu = s1 * (1.0f / F_N);
            float var = s2 * (1.0f / F_N) - mu * mu;
            float rs = rsqrtf(var + LN_EPS);
            union { int4 i; f16x8 h; } hx;
            #pragma unroll
            for (int j = 0; j < 8; j++)
                hx.h[j] = (f16)((acc[ii][j] - mu) * rs * sScale[f0 + j] + sBias[f0 + j]);
            int byte = (fg * 16) ^ ((r & 7) << 4);
            *(int4*)(smem + SM_X + r * 256 + byte) = hx.i;
        }
    }
    __syncthreads();

    // ---- main loop: 16 chunks of 32 hidden units ----
    const int wr = wid >> 1, wc = wid & 1;   // wave grid 4 (rows) x 2
    f32x4 acc2[2][4];
    #pragma unroll
    for (int mr = 0; mr < 2; mr++)
        #pragma unroll
        for (int nc = 0; nc < 4; nc++)
            acc2[mr][nc] = (f32x4){0.f, 0.f, 0.f, 0.f};

    for (int ch = 0; ch < 16; ch++) {
        const int h0 = ch * 32;
        // stage W1 chunk [32 n][128 k] (256B rows) + W2 chunk [128 f][32 h] (64B rows)
        {
            int n = t >> 4, sg = t & 15;                 // 32 x 16 x 16B = 8KB
            int4 v1 = *(const int4*)(gW1T + (size_t)(h0 + n) * F_N + sg * 8);
            *(int4*)(smem + SM_W1 + n * 256 + ((sg * 16) ^ ((n & 7) << 4))) = v1;
            int f = t >> 2, sg2 = t & 3;                 // 128 x 4 x 16B = 8KB
            int4 v2 = *(const int4*)(gW2C + (size_t)ch * 4096 + f * 32 + sg2 * 8);
            *(int4*)(smem + SM_W2 + f * 64 + ((sg2 * 16) ^ ((f & 3) << 4))) = v2;
        }
        __syncthreads();

        // GEMM1: H[128r x 32h] = X @ W1ch ; wave tile 32r x 16h
        f32x4 acc1[2];
        acc1[0] = (f32x4){0.f, 0.f, 0.f, 0.f};
        acc1[1] = (f32x4){0.f, 0.f, 0.f, 0.f};
        __builtin_amdgcn_s_setprio(1);
        #pragma unroll
        for (int ks = 0; ks < 4; ks++) {
            int n = wc * 16 + (lane & 15);
            int bbyte = (ks * 64 + (lane >> 4) * 16) ^ ((n & 7) << 4);
            f16x8 bfr = ldfrag(smem + SM_W1 + n * 256 + bbyte);
            #pragma unroll
            for (int mr = 0; mr < 2; mr++) {
                int r = wr * 32 + mr * 16 + (lane & 15);
                int abyte = (ks * 64 + (lane >> 4) * 16) ^ ((r & 7) << 4);
                f16x8 afr = ldfrag(smem + SM_X + r * 256 + abyte);
                acc1[mr] = __builtin_amdgcn_mfma_f32_16x16x32_f16(afr, bfr, acc1[mr], 0, 0, 0);
            }
        }
        __builtin_amdgcn_s_setprio(0);
        // bias + relu -> H (f16, 64B rows)
        {
            int jl = wc * 16 + (lane & 15);
            float b1v = sB1[h0 + jl];
            #pragma unroll
            for (int mr = 0; mr < 2; mr++)
                #pragma unroll
                for (int reg = 0; reg < 4; reg++) {
                    int r2 = wr * 32 + mr * 16 + (lane >> 4) * 4 + reg;
                    float h = fmaxf(acc1[mr][reg] + b1v, 0.f);
                    int byte = (jl * 2) ^ ((r2 & 3) << 4);
                    *(f16*)(smem + SM_H + r2 * 64 + byte) = (f16)h;
                }
        }
        __syncthreads();

        // GEMM2: acc2 += H @ W2ch ; K=32 (one MFMA K-step); wave tile 32r x 64f
        __builtin_amdgcn_s_setprio(1);
        {
            f16x8 afr2[2], bfr2[4];
            #pragma unroll
            for (int mr = 0; mr < 2; mr++) {
                int r = wr * 32 + mr * 16 + (lane & 15);
                int byte = ((lane >> 4) * 16) ^ ((r & 3) << 4);
                afr2[mr] = ldfrag(smem + SM_H + r * 64 + byte);
            }
            #pragma unroll
            for (int nc = 0; nc < 4; nc++) {
                int f = wc * 64 + nc * 16 + (lane & 15);
                int byte = ((lane >> 4) * 16) ^ ((f & 3) << 4);
                bfr2[nc] = ldfrag(smem + SM_W2 + f * 64 + byte);
            }
            #pragma unroll
            for (int mr = 0; mr < 2; mr++)
                #pragma unroll
                for (int nc = 0; nc < 4; nc++)
                    acc2[mr][nc] = __builtin_amdgcn_mfma_f32_16x16x32_f16(
                        afr2[mr], bfr2[nc], acc2[mr][nc], 0, 0, 0);
        }
        __builtin_amdgcn_s_setprio(0);
        __syncthreads();
    }

    // ---- epilogue: out[a,b,f] = E (NT re-read) + acc2 + b2 ----
    #pragma unroll
    for (int mr = 0; mr < 2; mr++)
        #pragma unroll
        for (int nc = 0; nc < 4; nc++)
            #pragma unroll
            for (int reg = 0; reg < 4; reg++) {
                int r = wr * 32 + mr * 16 + (lane >> 4) * 4 + reg;
                int f = wc * 64 + nc * 16 + (lane & 15);
                int a = a0 + (r >> 3), b = b0 + (r & 7);
                size_t idx = ((size_t)a * A_N + b) * F_N + f;
                float e = __builtin_nontemporal_load(out + idx);
                __builtin_nontemporal_store(e + acc2[mr][nc][reg] + sB2[f], out + idx);
            }
}

extern "C" void kernel_launch(void* const* d_in, const int* in_sizes, int n_in,
                              void* d_out, int out_size, void* d_ws, size_t ws_size,
                              hipStream_t stream) {
    const void* node_vec  = d_in[0];
    const void* edge_vec  = d_in[1];
    const void* node_mask = d_in[2];
    // d_in[3] edge_mask: unused by reference
    const void* op_scale  = d_in[4];
    const void* op_bias   = d_in[5];
    const void* w_left    = d_in[6];
    const void* b_left    = d_in[7];
    const void* w_right   = d_in[8];
    const void* b_right   = d_in[9];
    const void* w_out     = d_in[10];
    const void* b_out     = d_in[11];
    const void* tr_scale  = d_in[12];
    const void* tr_bias   = d_in[13];
    const void* w_t1      = d_in[14];
    const void* b_t1      = d_in[15];
    const void* w_t2      = d_in[16];
    const void* b_t2      = d_in[17];
    float* out = (float*)d_out;
    (void)d_ws; (void)ws_size; (void)in_sizes; (void)n_in; (void)out_size;

    hipLaunchKernelGGL(k_leftright, dim3(A_N), dim3(128), 0, stream,
                       node_vec, node_mask, op_scale, op_bias,
                       w_left, b_left, w_right, b_right);
    hipLaunchKernelGGL(k_M, dim3(A_N), dim3(128), 0, stream, w_out, node_mask);
    hipLaunchKernelGGL(k_wt, dim3(256), dim3(256), 0, stream, w_t1, w_t2, node_mask);
    hipLaunchKernelGGL(k_fused, dim3((A_N / 8) * (A_N / 16)), dim3(512), 0, stream,
                       edge_vec, b_out, tr_scale, tr_bias, b_t1, b_t2, node_mask, out);
}

// Round 5
// 378.090 us; speedup vs baseline: 2.7129x; 1.6188x over previous
//
#include <hip/hip_runtime.h>
#include <stdint.h>
#include <stddef.h>

#define A_N 384
#define F_N 128
#define C_N 32
#define H_N 512
#define LN_EPS 1e-5f

typedef unsigned short u16;
typedef _Float16 f16;
typedef f16 f16x8 __attribute__((ext_vector_type(8)));
typedef float f32x4 __attribute__((ext_vector_type(4)));

// ---- scratch in static device memory (d_ws unused) ----
__device__ float g_right[A_N * C_N];        // right proj, fp32 (k_M input)
__device__ f16   gLh[A_N * C_N];            // left proj, f16  [a][c]
__device__ f16   gMh[A_N * F_N * C_N];      // [b][f][c] f16 (c-contiguous = MFMA B-frag ready)
__device__ f16   gW1T[H_N * F_N];           // [h][k] = w_t1[k][h]
__device__ f16   gW2C[H_N * F_N];           // [ch][f][hh] = w_t2[ch*32+hh][f]

__device__ __forceinline__ float b2f(u16 u) {
    union { float f; uint32_t i; } v; v.i = ((uint32_t)u) << 16; return v.f;
}
__device__ __forceinline__ float ld(const void* p, int idx, bool isbf) {
    if (isbf) return b2f(((const u16*)p)[idx]);
    return ((const float*)p)[idx];
}
__device__ __forceinline__ bool probe_bf16(const void* node_mask) {
    return ((const u16*)node_mask)[0] == 0x3F80u;   // 1.0 bf16; fp32 LE low half is 0x0000
}
__device__ __forceinline__ f16x8 ldfrag(const void* p) {
    union { int4 i; f16x8 h; } u; u.i = *(const int4*)p; return u.h;
}

// ---------------- K1: node LN + left/right projections ----------------
__global__ void k_leftright(const void* __restrict__ node_vec, const void* __restrict__ node_mask,
                            const void* __restrict__ op_scale, const void* __restrict__ op_bias,
                            const void* __restrict__ w_left, const void* __restrict__ b_left,
                            const void* __restrict__ w_right, const void* __restrict__ b_right) {
    bool isbf = probe_bf16(node_mask);
    int a = blockIdx.x;
    int f = threadIdx.x;            // 128 threads = 2 waves
    __shared__ float sAct[F_N];
    __shared__ float sRed[4];
    float x = ld(node_vec, a * F_N + f, isbf);
    float s1 = x, s2 = x * x;
    for (int o = 1; o < 64; o <<= 1) { s1 += __shfl_xor(s1, o); s2 += __shfl_xor(s2, o); }
    int wv = threadIdx.x >> 6;
    if ((threadIdx.x & 63) == 0) { sRed[wv * 2] = s1; sRed[wv * 2 + 1] = s2; }
    __syncthreads();
    float sum = sRed[0] + sRed[2], sq = sRed[1] + sRed[3];
    float mu = sum * (1.0f / F_N);
    float var = sq * (1.0f / F_N) - mu * mu;
    float rs = rsqrtf(var + LN_EPS);
    sAct[f] = (x - mu) * rs * ld(op_scale, f, isbf) + ld(op_bias, f, isbf);
    __syncthreads();
    if (threadIdx.x < 64) {
        int c = threadIdx.x & 31;
        bool isL = threadIdx.x < 32;
        const void* W = isL ? w_left : w_right;
        const void* B = isL ? b_left : b_right;
        float acc = ld(B, c, isbf);
        for (int ff = 0; ff < F_N; ff++) acc += sAct[ff] * ld(W, ff * C_N + c, isbf);
        acc *= ld(node_mask, a, isbf);
        if (isL) gLh[a * C_N + c] = (f16)acc;
        else     g_right[a * C_N + c] = acc;
    }
}

// ---------------- K2: prep — M (f16, coalesced store) + weight transposes ----------------
// blocks [0,384): M[b][f][c] = sum_d right[b,d] * w_out[(c*32+d), f]  -> gMh (via LDS transpose)
// blocks [384,896): gW1T / gW2C fills
__global__ void k_prep(const void* __restrict__ w_out, const void* __restrict__ w_t1,
                       const void* __restrict__ w_t2, const void* __restrict__ node_mask) {
    bool isbf = probe_bf16(node_mask);
    __shared__ float sR[C_N];
    __shared__ f16 sT[F_N * C_N];            // 8 KB staging
    if (blockIdx.x < A_N) {
        int b = blockIdx.x;
        int f = threadIdx.x;                 // 128 threads
        if (f < C_N) sR[f] = g_right[b * C_N + f];
        __syncthreads();
        float acc[C_N];
        #pragma unroll
        for (int c = 0; c < C_N; c++) acc[c] = 0.f;
        for (int d = 0; d < C_N; d++) {
            float rv = sR[d];
            #pragma unroll
            for (int c = 0; c < C_N; c++)
                acc[c] += rv * ld(w_out, (c * C_N + d) * F_N + f, isbf);
        }
        #pragma unroll
        for (int c = 0; c < C_N; c++) sT[f * C_N + c] = (f16)acc[c];
        __syncthreads();
        // coalesced 16B store of the whole 8KB slab
        const int4* src = (const int4*)sT;
        int4* dst = (int4*)(gMh + (size_t)b * F_N * C_N);
        #pragma unroll
        for (int i = 0; i < 4; i++) dst[i * 128 + threadIdx.x] = src[i * 128 + threadIdx.x];
    } else {
        int t = (blockIdx.x - A_N) * 128 + threadIdx.x;   // 0..65535
        int h = t >> 7, k = t & 127;
        gW1T[t] = (f16)ld(w_t1, k * H_N + h, isbf);
        int ch = t >> 12, f2 = (t >> 5) & 127, hh = t & 31;
        gW2C[t] = (f16)ld(w_t2, (ch * 32 + hh) * F_N + f2, isbf);
    }
}

// ---------------- K3: fused outer-product + edge + LN + MLP + residual ----------------
// 256 threads (4 waves), tile = 64 rows = 4 b x 16 a, b-major: r = b_local*16 + a_local.
// Wave grid 2x2: wr picks 2-b row group (32 rows), wc picks 64-f half.
// Phase 1 (all MFMA-layout-native, E never leaves registers):
//   acc2[bb][nc] = mfma(left[16a x 32c], Mh[b][f-tile][c], 0) + edge + bout   == E fragment
//   LN in-register: in-thread partial over nc, 16-lane shfl reduce, one LDS cross-wc exchange.
//   X = LN(E) -> sX (f16, swizzled).  acc2 keeps E; epilogue adds b2 + MLP and writes out ONCE.
// Chunk loop: 16 x 32h. W1 [32n][256B swz]; W2/H use 72B rows (stride 18 dwords, bank-clean).
// LDS 42.5 KB -> 3 blocks/CU; launch_bounds(256,3) -> VGPR cap ~168, demand ~110 -> no spill.
#define SM_X    0        // 64 x 256B = 16384
#define SM_W1   16384    // 8192   (phase 1 overlay: sRed 1024B)
#define SM_RED  16384
#define SM_W2   24576    // 128 x 72 = 9216
#define SM_H    33792    // 64 x 72  = 4608
#define SM_B1   38400    // 512 floats
#define SM_SCL  40448
#define SM_BIA  40960
#define SM_B2   41472
#define SM_BOUT 41984
#define SM_TOT  42496

__global__ __launch_bounds__(256, 3) void k_fused(
    const void* __restrict__ edge_vec, const void* __restrict__ b_out,
    const void* __restrict__ tr_scale, const void* __restrict__ tr_bias,
    const void* __restrict__ b_t1, const void* __restrict__ b_t2,
    const void* __restrict__ node_mask, float* __restrict__ out)
{
    bool isbf = probe_bf16(node_mask);
    __shared__ __align__(16) unsigned char smem[SM_TOT];
    float* sRed   = (float*)(smem + SM_RED);
    float* sB1    = (float*)(smem + SM_B1);
    float* sScale = (float*)(smem + SM_SCL);
    float* sBias  = (float*)(smem + SM_BIA);
    float* sB2    = (float*)(smem + SM_B2);
    float* sBout  = (float*)(smem + SM_BOUT);

    const int t = threadIdx.x;               // 256 threads = 4 waves
    const int lane = t & 63, wid = t >> 6;
    const int g = lane >> 4, fc = lane & 15;
    const int wr = wid >> 1, wc = wid & 1;

    // Bijective XCD remap: 2304 blocks = 8 xcd x (12 bx x 24 by); each XCD owns 12
    // consecutive b-tiles -> its gMh slice (48 b x 8KB = 384KB) stays L2-resident.
    const int L = blockIdx.x;
    const int xcd = L & 7, pos = L >> 3;          // pos 0..287
    const int bx = xcd * 12 + (pos % 12);         // 0..95
    const int by = pos / 12;                      // 0..23
    const int a0 = by * 16, b0 = bx * 4;

    // ---- phase 0: consts ----
    sB1[t]       = ld(b_t1, t, isbf);
    sB1[t + 256] = ld(b_t1, t + 256, isbf);
    if (t < 128) {
        sScale[t] = ld(tr_scale, t, isbf);
        sBias[t]  = ld(tr_bias, t, isbf);
        sB2[t]    = ld(b_t2, t, isbf);
        sBout[t]  = ld(b_out, t, isbf);
    }
    __syncthreads();

    // ---- phase 1: E via MFMA, directly in accumulator layout ----
    f32x4 acc2[2][4];
    const f32x4 zero4 = (f32x4){0.f, 0.f, 0.f, 0.f};
    // A-frag: left rows a0..a0+15, k=c. lane: row=fc, k=g*8..+8 (16B contiguous)
    f16x8 aL = ldfrag(gLh + (a0 + fc) * C_N + g * 8);
    #pragma unroll
    for (int bb = 0; bb < 2; bb++) {
        int b = b0 + wr * 2 + bb;
        #pragma unroll
        for (int nc = 0; nc < 4; nc++) {
            int f = wc * 64 + nc * 16 + fc;
            // B-frag: B[k=c][col=f] = M[b][f][c]; lane: col=fc, k=g*8..+8 (16B contiguous)
            f16x8 bM = ldfrag(gMh + ((size_t)(b * F_N + f)) * C_N + g * 8);
            acc2[bb][nc] = __builtin_amdgcn_mfma_f32_16x16x32_f16(aL, bM, zero4, 0, 0, 0);
        }
    }
    // += edge + bout  (C/D layout: row a_local = g*4+reg, col f)
    #pragma unroll
    for (int bb = 0; bb < 2; bb++) {
        int b = b0 + wr * 2 + bb;
        #pragma unroll
        for (int nc = 0; nc < 4; nc++) {
            int f = wc * 64 + nc * 16 + fc;
            float bo = sBout[f];
            #pragma unroll
            for (int rg = 0; rg < 4; rg++) {
                int a = a0 + g * 4 + rg;
                acc2[bb][nc][rg] += ld(edge_vec, (a * A_N + b) * F_N + f, isbf) + bo;
            }
        }
    }
    // in-register LayerNorm: partials over nc, 16-lane reduce, cross-wc via sRed
    float pA[2][4], qA[2][4];
    #pragma unroll
    for (int bb = 0; bb < 2; bb++)
        #pragma unroll
        for (int rg = 0; rg < 4; rg++) {
            float e0 = acc2[bb][0][rg], e1 = acc2[bb][1][rg];
            float e2 = acc2[bb][2][rg], e3 = acc2[bb][3][rg];
            float p = e0 + e1 + e2 + e3;
            float q = e0 * e0 + e1 * e1 + e2 * e2 + e3 * e3;
            p += __shfl_xor(p, 1); q += __shfl_xor(q, 1);
            p += __shfl_xor(p, 2); q += __shfl_xor(q, 2);
            p += __shfl_xor(p, 4); q += __shfl_xor(q, 4);
            p += __shfl_xor(p, 8); q += __shfl_xor(q, 8);
            pA[bb][rg] = p; qA[bb][rg] = q;
            if (fc == 0) {
                int r = wr * 32 + bb * 16 + g * 4 + rg;
                sRed[r * 4 + wc * 2]     = p;
                sRed[r * 4 + wc * 2 + 1] = q;
            }
        }
    __syncthreads();
    float muA[2][4], rsA[2][4];
    #pragma unroll
    for (int bb = 0; bb < 2; bb++)
        #pragma unroll
        for (int rg = 0; rg < 4; rg++) {
            int r = wr * 32 + bb * 16 + g * 4 + rg;
            float s1 = pA[bb][rg] + sRed[r * 4 + (wc ^ 1) * 2];
            float s2 = qA[bb][rg] + sRed[r * 4 + (wc ^ 1) * 2 + 1];
            float mu = s1 * (1.0f / F_N);
            float var = s2 * (1.0f / F_N) - mu * mu;
            muA[bb][rg] = mu;
            rsA[bb][rg] = rsqrtf(var + LN_EPS);
        }
    // X = LN(E) -> sX (f16, swizzled rows 256B)
    #pragma unroll
    for (int bb = 0; bb < 2; bb++)
        #pragma unroll
        for (int nc = 0; nc < 4; nc++) {
            int f = wc * 64 + nc * 16 + fc;
            float sc = sScale[f], bi = sBias[f];
            #pragma unroll
            for (int rg = 0; rg < 4; rg++) {
                int r = wr * 32 + bb * 16 + g * 4 + rg;
                float x = (acc2[bb][nc][rg] - muA[bb][rg]) * rsA[bb][rg] * sc + bi;
                *(f16*)(smem + SM_X + r * 256 + ((f * 2) ^ ((r & 7) << 4))) = (f16)x;
            }
        }
    __syncthreads();   // sRed dead -> W1 region reusable

    // ---- chunk loop: 16 x 32 hidden units ----
    for (int ch = 0; ch < 16; ch++) {
        const int h0 = ch * 32;
        {   // stage W1 [32n][256B swz] + W2 [128f][72B rows]
            int n = t >> 3, sg = t & 7;
            const int4* s1p = (const int4*)(gW1T + (size_t)(h0 + n) * F_N) + sg * 2;
            int bA = (sg * 32) ^ ((n & 7) << 4);
            int bB = (sg * 32 + 16) ^ ((n & 7) << 4);
            *(int4*)(smem + SM_W1 + n * 256 + bA) = s1p[0];
            *(int4*)(smem + SM_W1 + n * 256 + bB) = s1p[1];
            int fR = t >> 1, s2g = t & 1;
            const int4* s2p = (const int4*)(gW2C + (size_t)ch * 4096 + fR * 32) + s2g * 2;
            *(int4*)(smem + SM_W2 + fR * 72 + s2g * 32)      = s2p[0];
            *(int4*)(smem + SM_W2 + fR * 72 + s2g * 32 + 16) = s2p[1];
        }
        __syncthreads();

        // GEMM1: H[64r x 32h] = X @ W1ch ; wave tile 32r x 16h
        f32x4 acc1[2];
        acc1[0] = zero4; acc1[1] = zero4;
        __builtin_amdgcn_s_setprio(1);
        #pragma unroll
        for (int ks = 0; ks < 4; ks++) {
            int n = wc * 16 + fc;
            f16x8 bfr = ldfrag(smem + SM_W1 + n * 256 + ((ks * 64 + g * 16) ^ ((n & 7) << 4)));
            #pragma unroll
            for (int mr = 0; mr < 2; mr++) {
                int r = wr * 32 + mr * 16 + fc;
                f16x8 afr = ldfrag(smem + SM_X + r * 256 + ((ks * 64 + g * 16) ^ ((r & 7) << 4)));
                acc1[mr] = __builtin_amdgcn_mfma_f32_16x16x32_f16(afr, bfr, acc1[mr], 0, 0, 0);
            }
        }
        __builtin_amdgcn_s_setprio(0);
        {   // bias + relu -> H (f16, 72B rows)
            int jl = wc * 16 + fc;
            float b1v = sB1[h0 + jl];
            #pragma unroll
            for (int mr = 0; mr < 2; mr++)
                #pragma unroll
                for (int rg = 0; rg < 4; rg++) {
                    int r2 = wr * 32 + mr * 16 + g * 4 + rg;
                    *(f16*)(smem + SM_H + r2 * 72 + jl * 2) =
                        (f16)fmaxf(acc1[mr][rg] + b1v, 0.f);
                }
        }
        __syncthreads();

        // GEMM2: acc2 += H @ W2ch ; K=32 single step; wave tile 32r x 64f
        __builtin_amdgcn_s_setprio(1);
        {
            f16x8 afr2[2], bfr2[4];
            #pragma unroll
            for (int mr = 0; mr < 2; mr++) {
                int r = wr * 32 + mr * 16 + fc;
                afr2[mr] = ldfrag(smem + SM_H + r * 72 + g * 16);
            }
            #pragma unroll
            for (int nc = 0; nc < 4; nc++) {
                int fR = wc * 64 + nc * 16 + fc;
                bfr2[nc] = ldfrag(smem + SM_W2 + fR * 72 + g * 16);
            }
            #pragma unroll
            for (int mr = 0; mr < 2; mr++)
                #pragma unroll
                for (int nc = 0; nc < 4; nc++)
                    acc2[mr][nc] = __builtin_amdgcn_mfma_f32_16x16x32_f16(
                        afr2[mr], bfr2[nc], acc2[mr][nc], 0, 0, 0);
        }
        __builtin_amdgcn_s_setprio(0);
        __syncthreads();
    }

    // ---- epilogue: out = E (in acc2) + b2 + MLP, written ONCE, coalesced 64B runs ----
    #pragma unroll
    for (int bb = 0; bb < 2; bb++) {
        int b = b0 + wr * 2 + bb;
        #pragma unroll
        for (int nc = 0; nc < 4; nc++) {
            int f = wc * 64 + nc * 16 + fc;
            float b2v = sB2[f];
            #pragma unroll
            for (int rg = 0; rg < 4; rg++) {
                int a = a0 + g * 4 + rg;
                out[((size_t)a * A_N + b) * F_N + f] = acc2[bb][nc][rg] + b2v;
            }
        }
    }
}

extern "C" void kernel_launch(void* const* d_in, const int* in_sizes, int n_in,
                              void* d_out, int out_size, void* d_ws, size_t ws_size,
                              hipStream_t stream) {
    const void* node_vec  = d_in[0];
    const void* edge_vec  = d_in[1];
    const void* node_mask = d_in[2];
    // d_in[3] edge_mask: unused by reference
    const void* op_scale  = d_in[4];
    const void* op_bias   = d_in[5];
    const void* w_left    = d_in[6];
    const void* b_left    = d_in[7];
    const void* w_right   = d_in[8];
    const void* b_right   = d_in[9];
    const void* w_out     = d_in[10];
    const void* b_out     = d_in[11];
    const void* tr_scale  = d_in[12];
    const void* tr_bias   = d_in[13];
    const void* w_t1      = d_in[14];
    const void* b_t1      = d_in[15];
    const void* w_t2      = d_in[16];
    const void* b_t2      = d_in[17];
    float* out = (float*)d_out;
    (void)d_ws; (void)ws_size; (void)in_sizes; (void)n_in; (void)out_size;

    hipLaunchKernelGGL(k_leftright, dim3(A_N), dim3(128), 0, stream,
                       node_vec, node_mask, op_scale, op_bias,
                       w_left, b_left, w_right, b_right);
    hipLaunchKernelGGL(k_prep, dim3(A_N + 512), dim3(128), 0, stream,
                       w_out, w_t1, w_t2, node_mask);
    hipLaunchKernelGGL(k_fused, dim3(2304), dim3(256), 0, stream,
                       edge_vec, b_out, tr_scale, tr_bias, b_t1, b_t2, node_mask, out);
}